// Round 1
// baseline (751.347 us; speedup 1.0000x reference)
//
#include <hip/hip_runtime.h>
#include <hip/hip_bf16.h>

#define N_NODES 100000
#define N_EDGES 1600000
#define N_GRAPHS 128
#define IN_F 128
#define H_F 128
#define OUT_F 64
#define HID 10
#define NCLS 10

#define SCAN_ITEMS 1024  // per block (256 thr * 4)
#define SCAN_NB ((N_NODES + SCAN_ITEMS - 1) / SCAN_ITEMS)  // 98

// ---------------- degree histogram ----------------
__global__ void k_degrees(const int* __restrict__ src, const int* __restrict__ dst,
                          int* __restrict__ cnt_out, int* __restrict__ cnt_in) {
    int e = blockIdx.x * blockDim.x + threadIdx.x;
    if (e < N_EDGES) {
        atomicAdd(&cnt_out[src[e]], 1);
        atomicAdd(&cnt_in[dst[e]], 1);
    }
}

__global__ void k_rsqrt(const int* __restrict__ cnt_out, const int* __restrict__ cnt_in,
                        float* __restrict__ ro, float* __restrict__ ri) {
    int v = blockIdx.x * blockDim.x + threadIdx.x;
    if (v < N_NODES) {
        ro[v] = rsqrtf((float)max(cnt_out[v], 1));
        ri[v] = rsqrtf((float)max(cnt_in[v], 1));
    }
}

// ---------------- prefix scan (3-kernel) for CSR row_ptr ----------------
__global__ void k_scan1(const int* __restrict__ cnt, int* __restrict__ rp, int* __restrict__ bsum) {
    __shared__ int ts[256];
    int tid = threadIdx.x;
    int base = blockIdx.x * SCAN_ITEMS + tid * 4;
    int v[4];
    int s = 0;
#pragma unroll
    for (int i = 0; i < 4; i++) {
        int idx = base + i;
        v[i] = (idx < N_NODES) ? cnt[idx] : 0;
        s += v[i];
    }
    ts[tid] = s;
    __syncthreads();
    for (int off = 1; off < 256; off <<= 1) {
        int u = (tid >= off) ? ts[tid - off] : 0;
        __syncthreads();
        ts[tid] += u;
        __syncthreads();
    }
    int excl = ts[tid] - s;
    int run = excl;
#pragma unroll
    for (int i = 0; i < 4; i++) {
        run += v[i];
        int idx = base + i;
        if (idx < N_NODES) rp[idx + 1] = run;  // block-local inclusive
    }
    if (tid == 255) bsum[blockIdx.x] = ts[255];
}

__global__ void k_scan2(int* __restrict__ bsum, int nb) {
    if (threadIdx.x == 0 && blockIdx.x == 0) {
        int acc = 0;
        for (int i = 0; i < nb; i++) { int t = bsum[i]; bsum[i] = acc; acc += t; }
    }
}

__global__ void k_scan3(int* __restrict__ rp, const int* __restrict__ boffs) {
    int idx = blockIdx.x * blockDim.x + threadIdx.x;
    if (idx < N_NODES) rp[idx + 1] += boffs[idx / SCAN_ITEMS];
    if (idx == 0) rp[0] = 0;
}

__global__ void k_fill(const int* __restrict__ src, const int* __restrict__ dst,
                       const int* __restrict__ rp, int* __restrict__ fill,
                       int* __restrict__ cols) {
    int e = blockIdx.x * blockDim.x + threadIdx.x;
    if (e < N_EDGES) {
        int d = dst[e];
        int pos = rp[d] + atomicAdd(&fill[d], 1);
        cols[pos] = src[e];
    }
}

// ---------------- GEMM: G[v, cbase..cbase+63] = ro[v] * (X[v,:] @ W[:, cbase..cbase+63])
// K = 128 always. TOTF = row stride of W / Gout (128 or 64). Block: 256 thr, 32 rows x 64 cols.
template <int TOTF>
__global__ __launch_bounds__(256) void k_gemm(const float* __restrict__ X,
                                              const float* __restrict__ W,
                                              const float* __restrict__ ro,
                                              float* __restrict__ Gout) {
    __shared__ float Ws[128 * 64];   // 32 KB
    __shared__ float Xs[32 * 128];   // 16 KB
    const int tid = threadIdx.x;
    const int cbase = blockIdx.y * 64;
    // stage W columns [cbase, cbase+64)
    for (int i = tid; i < 128 * 64; i += 256) {
        int k = i >> 6, cc = i & 63;
        Ws[i] = W[k * TOTF + cbase + cc];
    }
    const int cp = tid & 31;        // col pair 0..31
    const int rg = tid >> 5;        // row group 0..7
    const int row0 = blockIdx.x * 32;  // N_NODES % 32 == 0, no guards needed
    // stage X rows [row0, row0+32) as float4
    {
        const float4* X4 = (const float4*)X;
        float4* Xs4 = (float4*)Xs;
        for (int i = tid; i < 32 * 32; i += 256) {
            int r = i >> 5, k4 = i & 31;
            Xs4[i] = X4[(size_t)(row0 + r) * 32 + k4];
        }
    }
    __syncthreads();
    const float2* Ws2 = (const float2*)Ws;
    float acc[4][2];
#pragma unroll
    for (int i = 0; i < 4; i++) { acc[i][0] = 0.f; acc[i][1] = 0.f; }
#pragma unroll 4
    for (int k = 0; k < 128; k++) {
        float2 w = Ws2[k * 32 + cp];
#pragma unroll
        for (int i = 0; i < 4; i++) {
            float xv = Xs[(rg * 4 + i) * 128 + k];
            acc[i][0] = fmaf(xv, w.x, acc[i][0]);
            acc[i][1] = fmaf(xv, w.y, acc[i][1]);
        }
    }
#pragma unroll
    for (int i = 0; i < 4; i++) {
        int row = row0 + rg * 4 + i;
        float s = ro[row];
        float2 o;
        o.x = acc[i][0] * s;
        o.y = acc[i][1] * s;
        *(float2*)&Gout[(size_t)row * TOTF + cbase + 2 * cp] = o;
    }
}

// ---------------- SpMM: H[v] = relu(ri[v] * sum_{s in nbr(v)} G[s] + bias) ----------------
template <int F>
__global__ __launch_bounds__(256) void k_spmm(const float* __restrict__ G,
                                              const int* __restrict__ rp,
                                              const int* __restrict__ cols,
                                              const float* __restrict__ ri,
                                              const float* __restrict__ bias,
                                              float* __restrict__ H) {
    const int lane = threadIdx.x & 63;
    const int wave = threadIdx.x >> 6;
    const int v = blockIdx.x * 4 + wave;   // N_NODES % 4 == 0
    if (v >= N_NODES) return;
    const int jb = rp[v], je = rp[v + 1];
    if constexpr (F == 128) {
        float ax = 0.f, ay = 0.f;
        int j = jb;
        for (; j + 1 < je; j += 2) {
            int s0 = cols[j], s1 = cols[j + 1];
            float2 g0 = *(const float2*)&G[(size_t)s0 * 128 + 2 * lane];
            float2 g1 = *(const float2*)&G[(size_t)s1 * 128 + 2 * lane];
            ax += g0.x + g1.x;
            ay += g0.y + g1.y;
        }
        if (j < je) {
            int s0 = cols[j];
            float2 g0 = *(const float2*)&G[(size_t)s0 * 128 + 2 * lane];
            ax += g0.x;
            ay += g0.y;
        }
        float r = ri[v];
        float2 b = *(const float2*)&bias[2 * lane];
        float2 o;
        o.x = fmaxf(fmaf(ax, r, b.x), 0.f);
        o.y = fmaxf(fmaf(ay, r, b.y), 0.f);
        *(float2*)&H[(size_t)v * 128 + 2 * lane] = o;
    } else {
        float a = 0.f;
        int j = jb;
        for (; j + 1 < je; j += 2) {
            int s0 = cols[j], s1 = cols[j + 1];
            a += G[(size_t)s0 * 64 + lane] + G[(size_t)s1 * 64 + lane];
        }
        if (j < je) a += G[(size_t)cols[j] * 64 + lane];
        float o = fmaxf(fmaf(a, ri[v], bias[lane]), 0.f);
        H[(size_t)v * 64 + lane] = o;
    }
}

// ---------------- graph ranges (graph_ids sorted) ----------------
__global__ void k_bounds(const int* __restrict__ gid, int* __restrict__ gstart, int* __restrict__ gend) {
    int v = blockIdx.x * blockDim.x + threadIdx.x;
    if (v < N_NODES) {
        int g = gid[v];
        if (v == 0 || gid[v - 1] != g) gstart[g] = v;
        if (v == N_NODES - 1 || gid[v + 1] != g) gend[g] = v + 1;
    }
}

__global__ void k_pool(const float* __restrict__ h2, const int* __restrict__ gstart,
                       const int* __restrict__ gend, float* __restrict__ pooled) {
    int g = blockIdx.x;
    int c = threadIdx.x;  // 64
    int s = gstart[g], e = gend[g];
    float acc = 0.f;
    int v = s;
    for (; v + 3 < e; v += 4) {
        acc += h2[(size_t)v * 64 + c] + h2[(size_t)(v + 1) * 64 + c]
             + h2[(size_t)(v + 2) * 64 + c] + h2[(size_t)(v + 3) * 64 + c];
    }
    for (; v < e; v++) acc += h2[(size_t)v * 64 + c];
    int cnt = e - s;
    pooled[g * 64 + c] = acc / (float)max(cnt, 1);
}

// ---------------- MLP + softmax ----------------
__global__ void k_mlp(const float* __restrict__ pooled,
                      const float* __restrict__ fcW1, const float* __restrict__ fcb1,
                      const float* __restrict__ fcW2, const float* __restrict__ fcb2,
                      float* __restrict__ out) {
    __shared__ float p[64];
    __shared__ float z[10];
    __shared__ float l[10];
    __shared__ float red[2];
    int g = blockIdx.x;
    int t = threadIdx.x;  // 64
    p[t] = pooled[g * 64 + t];
    __syncthreads();
    if (t < 10) {
        float a = fcb1[t];
        for (int k = 0; k < 64; k++) a = fmaf(p[k], fcW1[k * 10 + t], a);
        z[t] = fmaxf(a, 0.f);
    }
    __syncthreads();
    if (t < 10) {
        float a = fcb2[t];
        for (int k = 0; k < 10; k++) a = fmaf(z[k], fcW2[k * 10 + t], a);
        l[t] = a;
    }
    __syncthreads();
    if (t == 0) {
        float m = l[0];
        for (int i = 1; i < 10; i++) m = fmaxf(m, l[i]);
        float ssum = 0.f;
        for (int i = 0; i < 10; i++) ssum += expf(l[i] - m);
        red[0] = m;
        red[1] = ssum;
    }
    __syncthreads();
    if (t < 10) out[g * 10 + t] = expf(l[t] - red[0]) / red[1];
}

// ---------------- host ----------------
extern "C" void kernel_launch(void* const* d_in, const int* in_sizes, int n_in,
                              void* d_out, int out_size, void* d_ws, size_t ws_size,
                              hipStream_t stream) {
    const float* feats = (const float*)d_in[0];
    const int* src = (const int*)d_in[1];
    const int* dst = (const int*)d_in[2];
    const int* gid = (const int*)d_in[3];
    const float* W1 = (const float*)d_in[4];
    const float* b1 = (const float*)d_in[5];
    const float* W2 = (const float*)d_in[6];
    const float* b2 = (const float*)d_in[7];
    const float* fcW1 = (const float*)d_in[8];
    const float* fcb1 = (const float*)d_in[9];
    const float* fcW2 = (const float*)d_in[10];
    const float* fcb2 = (const float*)d_in[11];
    float* out = (float*)d_out;

    // workspace layout
    char* w = (char*)d_ws;
    size_t off = 0;
    auto alloc = [&](size_t bytes) -> void* {
        void* p = w + off;
        off = (off + bytes + 255) & ~(size_t)255;
        return p;
    };
    int* cnt_out = (int*)alloc(N_NODES * 4);
    int* cnt_in  = (int*)alloc(N_NODES * 4);
    int* fill    = (int*)alloc(N_NODES * 4);
    int* rp      = (int*)alloc((N_NODES + 1) * 4);
    float* ro    = (float*)alloc(N_NODES * 4);
    float* ri    = (float*)alloc(N_NODES * 4);
    int* cols    = (int*)alloc(N_EDGES * 4);
    int* bsum    = (int*)alloc(SCAN_NB * 4);
    int* gstart  = (int*)alloc(N_GRAPHS * 4);
    int* gend    = (int*)alloc(N_GRAPHS * 4);
    float* pooled = (float*)alloc(N_GRAPHS * OUT_F * 4);
    float* bufA  = (float*)alloc((size_t)N_NODES * 128 * 4);  // g1, later g2+h2
    float* bufB  = (float*)alloc((size_t)N_NODES * 128 * 4);  // h1
    float* g1 = bufA;
    float* h1 = bufB;
    float* g2 = bufA;                       // N*64, overwrites dead g1
    float* h2 = bufA + (size_t)N_NODES * 64;  // second half of bufA

    // zero accumulators
    hipMemsetAsync(cnt_out, 0, N_NODES * 4, stream);
    hipMemsetAsync(cnt_in, 0, N_NODES * 4, stream);
    hipMemsetAsync(fill, 0, N_NODES * 4, stream);
    hipMemsetAsync(gstart, 0, N_GRAPHS * 4, stream);
    hipMemsetAsync(gend, 0, N_GRAPHS * 4, stream);

    // degrees + norms
    k_degrees<<<N_EDGES / 256, 256, 0, stream>>>(src, dst, cnt_out, cnt_in);
    k_rsqrt<<<(N_NODES + 255) / 256, 256, 0, stream>>>(cnt_out, cnt_in, ro, ri);

    // CSR build (by dst)
    k_scan1<<<SCAN_NB, 256, 0, stream>>>(cnt_in, rp, bsum);
    k_scan2<<<1, 64, 0, stream>>>(bsum, SCAN_NB);
    k_scan3<<<(N_NODES + 255) / 256, 256, 0, stream>>>(rp, bsum);
    k_fill<<<N_EDGES / 256, 256, 0, stream>>>(src, dst, rp, fill, cols);

    // layer 1: g1 = ro * (feats @ W1); h1 = relu(ri * agg(g1) + b1)
    k_gemm<128><<<dim3(N_NODES / 32, 2), 256, 0, stream>>>(feats, W1, ro, g1);
    k_spmm<128><<<N_NODES / 4, 256, 0, stream>>>(g1, rp, cols, ri, b1, h1);

    // layer 2: g2 = ro * (h1 @ W2); h2 = relu(ri * agg(g2) + b2)
    k_gemm<64><<<dim3(N_NODES / 32, 1), 256, 0, stream>>>(h1, W2, ro, g2);
    k_spmm<64><<<N_NODES / 4, 256, 0, stream>>>(g2, rp, cols, ri, b2, h2);

    // pooling + MLP + softmax
    k_bounds<<<(N_NODES + 255) / 256, 256, 0, stream>>>(gid, gstart, gend);
    k_pool<<<N_GRAPHS, 64, 0, stream>>>(h2, gstart, gend, pooled);
    k_mlp<<<N_GRAPHS, 64, 0, stream>>>(pooled, fcW1, fcb1, fcW2, fcb2, out);
}

// Round 2
// 611.400 us; speedup vs baseline: 1.2289x; 1.2289x over previous
//
#include <hip/hip_runtime.h>
#include <hip/hip_bf16.h>

#define N_NODES 100000
#define N_EDGES 1600000
#define N_GRAPHS 128
#define IN_F 128
#define H_F 128
#define OUT_F 64
#define HID 10
#define NCLS 10
#define MAXDEG 64   // in-degree ~ Poisson(16); P(deg>64) ~ 1e-20 per node

// ---------------- single-pass padded-CSR build ----------------
// cnt_out[s] += 1 ; idx = cnt_in[d]++ ; colsp[d*64+idx] = s
__global__ void k_build(const int* __restrict__ src, const int* __restrict__ dst,
                        int* __restrict__ cnt_out, int* __restrict__ cnt_in,
                        int* __restrict__ colsp) {
    int e = blockIdx.x * blockDim.x + threadIdx.x;
    if (e < N_EDGES) {
        int s = src[e];
        int d = dst[e];
        atomicAdd(&cnt_out[s], 1);
        int idx = atomicAdd(&cnt_in[d], 1);
        if (idx < MAXDEG) colsp[d * MAXDEG + idx] = s;
    }
}

__global__ void k_rsqrt(const int* __restrict__ cnt_out, const int* __restrict__ cnt_in,
                        float* __restrict__ ro, float* __restrict__ ri) {
    int v = blockIdx.x * blockDim.x + threadIdx.x;
    if (v < N_NODES) {
        ro[v] = rsqrtf((float)max(cnt_out[v], 1));
        ri[v] = rsqrtf((float)max(cnt_in[v], 1));
    }
}

// ---------------- GEMM: G[v, cbase..cbase+63] = ro[v] * (X[v,:] @ W[:, cbase..cbase+63])
// K = 128 always. TOTF = row stride of W / Gout (128 or 64). Block: 256 thr, 32 rows x 64 cols.
template <int TOTF>
__global__ __launch_bounds__(256) void k_gemm(const float* __restrict__ X,
                                              const float* __restrict__ W,
                                              const float* __restrict__ ro,
                                              float* __restrict__ Gout) {
    __shared__ float Ws[128 * 64];   // 32 KB
    __shared__ float Xs[32 * 128];   // 16 KB
    const int tid = threadIdx.x;
    const int cbase = blockIdx.y * 64;
    for (int i = tid; i < 128 * 64; i += 256) {
        int k = i >> 6, cc = i & 63;
        Ws[i] = W[k * TOTF + cbase + cc];
    }
    const int cp = tid & 31;        // col pair 0..31
    const int rg = tid >> 5;        // row group 0..7
    const int row0 = blockIdx.x * 32;  // N_NODES % 32 == 0
    {
        const float4* X4 = (const float4*)X;
        float4* Xs4 = (float4*)Xs;
        for (int i = tid; i < 32 * 32; i += 256) {
            int r = i >> 5, k4 = i & 31;
            Xs4[i] = X4[(size_t)(row0 + r) * 32 + k4];
        }
    }
    __syncthreads();
    const float2* Ws2 = (const float2*)Ws;
    float acc[4][2];
#pragma unroll
    for (int i = 0; i < 4; i++) { acc[i][0] = 0.f; acc[i][1] = 0.f; }
#pragma unroll 4
    for (int k = 0; k < 128; k++) {
        float2 w = Ws2[k * 32 + cp];
#pragma unroll
        for (int i = 0; i < 4; i++) {
            float xv = Xs[(rg * 4 + i) * 128 + k];
            acc[i][0] = fmaf(xv, w.x, acc[i][0]);
            acc[i][1] = fmaf(xv, w.y, acc[i][1]);
        }
    }
#pragma unroll
    for (int i = 0; i < 4; i++) {
        int row = row0 + rg * 4 + i;
        float s = ro[row];
        float2 o;
        o.x = acc[i][0] * s;
        o.y = acc[i][1] * s;
        *(float2*)&Gout[(size_t)row * TOTF + cbase + 2 * cp] = o;
    }
}

// ---------------- SpMM: H[v] = relu(ri[v] * sum_{s in nbr(v)} G[s] + bias) ----------------
// wave per dst node; neighbor list (<=64) loaded with ONE coalesced load, broadcast via shfl
template <int F>
__global__ __launch_bounds__(256) void k_spmm(const float* __restrict__ G,
                                              const int* __restrict__ cnt_in,
                                              const int* __restrict__ colsp,
                                              const float* __restrict__ ri,
                                              const float* __restrict__ bias,
                                              float* __restrict__ H) {
    const int lane = threadIdx.x & 63;
    const int wave = threadIdx.x >> 6;
    const int v = blockIdx.x * 4 + wave;   // N_NODES % 4 == 0
    if (v >= N_NODES) return;
    int deg = cnt_in[v];
    if (deg > MAXDEG) deg = MAXDEG;
    const int mycol = (lane < deg) ? colsp[v * MAXDEG + lane] : 0;
    if constexpr (F == 128) {
        float ax = 0.f, ay = 0.f;
        int j = 0;
        for (; j + 3 < deg; j += 4) {
            int s0 = __shfl(mycol, j);
            int s1 = __shfl(mycol, j + 1);
            int s2 = __shfl(mycol, j + 2);
            int s3 = __shfl(mycol, j + 3);
            float2 g0 = *(const float2*)&G[(size_t)s0 * 128 + 2 * lane];
            float2 g1 = *(const float2*)&G[(size_t)s1 * 128 + 2 * lane];
            float2 g2 = *(const float2*)&G[(size_t)s2 * 128 + 2 * lane];
            float2 g3 = *(const float2*)&G[(size_t)s3 * 128 + 2 * lane];
            ax += (g0.x + g1.x) + (g2.x + g3.x);
            ay += (g0.y + g1.y) + (g2.y + g3.y);
        }
        for (; j < deg; j++) {
            int s0 = __shfl(mycol, j);
            float2 g0 = *(const float2*)&G[(size_t)s0 * 128 + 2 * lane];
            ax += g0.x;
            ay += g0.y;
        }
        float r = ri[v];
        float2 b = *(const float2*)&bias[2 * lane];
        float2 o;
        o.x = fmaxf(fmaf(ax, r, b.x), 0.f);
        o.y = fmaxf(fmaf(ay, r, b.y), 0.f);
        *(float2*)&H[(size_t)v * 128 + 2 * lane] = o;
    } else {
        float a = 0.f;
        int j = 0;
        for (; j + 3 < deg; j += 4) {
            int s0 = __shfl(mycol, j);
            int s1 = __shfl(mycol, j + 1);
            int s2 = __shfl(mycol, j + 2);
            int s3 = __shfl(mycol, j + 3);
            a += (G[(size_t)s0 * 64 + lane] + G[(size_t)s1 * 64 + lane])
               + (G[(size_t)s2 * 64 + lane] + G[(size_t)s3 * 64 + lane]);
        }
        for (; j < deg; j++) {
            int s0 = __shfl(mycol, j);
            a += G[(size_t)s0 * 64 + lane];
        }
        float o = fmaxf(fmaf(a, ri[v], bias[lane]), 0.f);
        H[(size_t)v * 64 + lane] = o;
    }
}

// ---------------- graph ranges (graph_ids sorted) ----------------
__global__ void k_bounds(const int* __restrict__ gid, int* __restrict__ gstart, int* __restrict__ gend) {
    int v = blockIdx.x * blockDim.x + threadIdx.x;
    if (v < N_NODES) {
        int g = gid[v];
        if (v == 0 || gid[v - 1] != g) gstart[g] = v;
        if (v == N_NODES - 1 || gid[v + 1] != g) gend[g] = v + 1;
    }
}

__global__ void k_pool(const float* __restrict__ h2, const int* __restrict__ gstart,
                       const int* __restrict__ gend, float* __restrict__ pooled) {
    __shared__ float part[4][64];
    int g = blockIdx.x;
    int tid = threadIdx.x;       // 256
    int c = tid & 63;
    int w = tid >> 6;
    int s = gstart[g], e = gend[g];
    float acc = 0.f;
    for (int v = s + w; v < e; v += 4) acc += h2[(size_t)v * 64 + c];
    part[w][c] = acc;
    __syncthreads();
    if (tid < 64) {
        float t = part[0][tid] + part[1][tid] + part[2][tid] + part[3][tid];
        int cnt = e - s;
        pooled[g * 64 + tid] = t / (float)max(cnt, 1);
    }
}

// ---------------- MLP + softmax ----------------
__global__ void k_mlp(const float* __restrict__ pooled,
                      const float* __restrict__ fcW1, const float* __restrict__ fcb1,
                      const float* __restrict__ fcW2, const float* __restrict__ fcb2,
                      float* __restrict__ out) {
    __shared__ float p[64];
    __shared__ float z[10];
    __shared__ float l[10];
    __shared__ float red[2];
    int g = blockIdx.x;
    int t = threadIdx.x;  // 64
    p[t] = pooled[g * 64 + t];
    __syncthreads();
    if (t < 10) {
        float a = fcb1[t];
        for (int k = 0; k < 64; k++) a = fmaf(p[k], fcW1[k * 10 + t], a);
        z[t] = fmaxf(a, 0.f);
    }
    __syncthreads();
    if (t < 10) {
        float a = fcb2[t];
        for (int k = 0; k < 10; k++) a = fmaf(z[k], fcW2[k * 10 + t], a);
        l[t] = a;
    }
    __syncthreads();
    if (t == 0) {
        float m = l[0];
        for (int i = 1; i < 10; i++) m = fmaxf(m, l[i]);
        float ssum = 0.f;
        for (int i = 0; i < 10; i++) ssum += expf(l[i] - m);
        red[0] = m;
        red[1] = ssum;
    }
    __syncthreads();
    if (t < 10) out[g * 10 + t] = expf(l[t] - red[0]) / red[1];
}

// ---------------- host ----------------
extern "C" void kernel_launch(void* const* d_in, const int* in_sizes, int n_in,
                              void* d_out, int out_size, void* d_ws, size_t ws_size,
                              hipStream_t stream) {
    const float* feats = (const float*)d_in[0];
    const int* src = (const int*)d_in[1];
    const int* dst = (const int*)d_in[2];
    const int* gid = (const int*)d_in[3];
    const float* W1 = (const float*)d_in[4];
    const float* b1 = (const float*)d_in[5];
    const float* W2 = (const float*)d_in[6];
    const float* b2 = (const float*)d_in[7];
    const float* fcW1 = (const float*)d_in[8];
    const float* fcb1 = (const float*)d_in[9];
    const float* fcW2 = (const float*)d_in[10];
    const float* fcb2 = (const float*)d_in[11];
    float* out = (float*)d_out;

    // workspace layout
    char* w = (char*)d_ws;
    size_t off = 0;
    auto alloc = [&](size_t bytes) -> void* {
        void* p = w + off;
        off = (off + bytes + 255) & ~(size_t)255;
        return p;
    };
    int* cnt_out = (int*)alloc(N_NODES * 4);
    int* cnt_in  = (int*)alloc(N_NODES * 4);
    float* ro    = (float*)alloc(N_NODES * 4);
    float* ri    = (float*)alloc(N_NODES * 4);
    int* colsp   = (int*)alloc((size_t)N_NODES * MAXDEG * 4);  // 25.6 MB
    int* gstart  = (int*)alloc(N_GRAPHS * 4);
    int* gend    = (int*)alloc(N_GRAPHS * 4);
    float* pooled = (float*)alloc(N_GRAPHS * OUT_F * 4);
    float* bufA  = (float*)alloc((size_t)N_NODES * 128 * 4);  // g1, later g2+h2
    float* bufB  = (float*)alloc((size_t)N_NODES * 128 * 4);  // h1
    float* g1 = bufA;
    float* h1 = bufB;
    float* g2 = bufA;                         // N*64, overwrites dead g1
    float* h2 = bufA + (size_t)N_NODES * 64;  // second half of bufA

    hipMemsetAsync(cnt_out, 0, N_NODES * 4, stream);
    hipMemsetAsync(cnt_in, 0, N_NODES * 4, stream);
    hipMemsetAsync(gstart, 0, N_GRAPHS * 4, stream);
    hipMemsetAsync(gend, 0, N_GRAPHS * 4, stream);

    // single-pass padded CSR build (degrees + adjacency)
    k_build<<<N_EDGES / 256, 256, 0, stream>>>(src, dst, cnt_out, cnt_in, colsp);
    k_rsqrt<<<(N_NODES + 255) / 256, 256, 0, stream>>>(cnt_out, cnt_in, ro, ri);

    // layer 1: g1 = ro * (feats @ W1); h1 = relu(ri * agg(g1) + b1)
    k_gemm<128><<<dim3(N_NODES / 32, 2), 256, 0, stream>>>(feats, W1, ro, g1);
    k_spmm<128><<<N_NODES / 4, 256, 0, stream>>>(g1, cnt_in, colsp, ri, b1, h1);

    // layer 2: g2 = ro * (h1 @ W2); h2 = relu(ri * agg(g2) + b2)
    k_gemm<64><<<dim3(N_NODES / 32, 1), 256, 0, stream>>>(h1, W2, ro, g2);
    k_spmm<64><<<N_NODES / 4, 256, 0, stream>>>(g2, cnt_in, colsp, ri, b2, h2);

    // pooling + MLP + softmax
    k_bounds<<<(N_NODES + 255) / 256, 256, 0, stream>>>(gid, gstart, gend);
    k_pool<<<N_GRAPHS, 256, 0, stream>>>(h2, gstart, gend, pooled);
    k_mlp<<<N_GRAPHS, 64, 0, stream>>>(pooled, fcW1, fcb1, fcW2, fcb2, out);
}

// Round 3
// 543.050 us; speedup vs baseline: 1.3836x; 1.1259x over previous
//
#include <hip/hip_runtime.h>
#include <hip/hip_bf16.h>

#define N_NODES 100000
#define N_EDGES 1600000
#define N_GRAPHS 128
#define IN_F 128
#define H_F 128
#define OUT_F 64
#define HID 10
#define NCLS 10
#define MAXDEG 64   // in-degree ~ Poisson(16); P(deg>64) ~ 1e-20 per node

// ---------------- single-pass padded-CSR build ----------------
__global__ void k_build(const int* __restrict__ src, const int* __restrict__ dst,
                        int* __restrict__ cnt_out, int* __restrict__ cnt_in,
                        int* __restrict__ colsp) {
    int e = blockIdx.x * blockDim.x + threadIdx.x;
    if (e < N_EDGES) {
        int s = src[e];
        int d = dst[e];
        atomicAdd(&cnt_out[s], 1);
        int idx = atomicAdd(&cnt_in[d], 1);
        if (idx < MAXDEG) colsp[d * MAXDEG + idx] = s;
    }
}

// ---------------- GEMM: G[v, cbase..cbase+63] = rsqrt(deg_out[v]) * (X[v,:] @ W[:, cbase..+63])
// K = 128 always. TOTF = out-feature count (= W row stride = G row stride). X stride always 128.
// Output packed bf16. Block: 256 thr, 32 rows x 64 cols.
template <int TOTF>
__global__ __launch_bounds__(256) void k_gemm(const float* __restrict__ X,
                                              const float* __restrict__ W,
                                              const int* __restrict__ cnt_out,
                                              __hip_bfloat162* __restrict__ Gout) {
    __shared__ float Ws[128 * 64];   // 32 KB
    __shared__ float Xs[32 * 128];   // 16 KB
    const int tid = threadIdx.x;
    const int cbase = blockIdx.y * 64;
    for (int i = tid; i < 128 * 64; i += 256) {
        int k = i >> 6, cc = i & 63;
        Ws[i] = W[k * TOTF + cbase + cc];
    }
    const int cp = tid & 31;        // col pair 0..31
    const int rg = tid >> 5;        // row group 0..7
    const int row0 = blockIdx.x * 32;  // N_NODES % 32 == 0
    {
        const float4* X4 = (const float4*)X;
        float4* Xs4 = (float4*)Xs;
        for (int i = tid; i < 32 * 32; i += 256) {
            int r = i >> 5, k4 = i & 31;
            Xs4[i] = X4[(size_t)(row0 + r) * 32 + k4];
        }
    }
    __syncthreads();
    const float2* Ws2 = (const float2*)Ws;
    float acc[4][2];
#pragma unroll
    for (int i = 0; i < 4; i++) { acc[i][0] = 0.f; acc[i][1] = 0.f; }
#pragma unroll 4
    for (int k = 0; k < 128; k++) {
        float2 w = Ws2[k * 32 + cp];
#pragma unroll
        for (int i = 0; i < 4; i++) {
            float xv = Xs[(rg * 4 + i) * 128 + k];
            acc[i][0] = fmaf(xv, w.x, acc[i][0]);
            acc[i][1] = fmaf(xv, w.y, acc[i][1]);
        }
    }
#pragma unroll
    for (int i = 0; i < 4; i++) {
        int row = row0 + rg * 4 + i;
        float s = rsqrtf((float)max(cnt_out[row], 1));
        float2 o;
        o.x = acc[i][0] * s;
        o.y = acc[i][1] * s;
        Gout[(size_t)row * (TOTF / 2) + (cbase >> 1) + cp] = __float22bfloat162_rn(o);
    }
}

// ---------------- SpMM: H[v] = relu(rsqrt(deg_in[v]) * sum_{s in nbr(v)} G[s] + bias) ----------------
// wave per dst node; neighbor list (<=64) loaded with ONE masked coalesced load, broadcast via shfl.
// G is packed bf16.
template <int F>
__global__ __launch_bounds__(256) void k_spmm(const void* __restrict__ Gv,
                                              const int* __restrict__ cnt_in,
                                              const int* __restrict__ colsp,
                                              const float* __restrict__ bias,
                                              float* __restrict__ H) {
    const int lane = threadIdx.x & 63;
    const int wave = threadIdx.x >> 6;
    const int v = blockIdx.x * 4 + wave;   // N_NODES % 4 == 0
    if (v >= N_NODES) return;
    int cnt = cnt_in[v];
    int deg = min(cnt, MAXDEG);
    const int mycol = (lane < deg) ? colsp[v * MAXDEG + lane] : 0;
    const float r = rsqrtf((float)max(cnt, 1));
    if constexpr (F == 128) {
        // row = 128 bf16 = 64 uints; lane handles cols {2*lane, 2*lane+1}
        const unsigned int* G = (const unsigned int*)Gv;
        float ax = 0.f, ay = 0.f;
        int j = 0;
        for (; j + 3 < deg; j += 4) {
            int s0 = __shfl(mycol, j);
            int s1 = __shfl(mycol, j + 1);
            int s2 = __shfl(mycol, j + 2);
            int s3 = __shfl(mycol, j + 3);
            unsigned int u0 = G[(size_t)s0 * 64 + lane];
            unsigned int u1 = G[(size_t)s1 * 64 + lane];
            unsigned int u2 = G[(size_t)s2 * 64 + lane];
            unsigned int u3 = G[(size_t)s3 * 64 + lane];
            ax += __uint_as_float(u0 << 16) + __uint_as_float(u1 << 16)
                + __uint_as_float(u2 << 16) + __uint_as_float(u3 << 16);
            ay += __uint_as_float(u0 & 0xffff0000u) + __uint_as_float(u1 & 0xffff0000u)
                + __uint_as_float(u2 & 0xffff0000u) + __uint_as_float(u3 & 0xffff0000u);
        }
        for (; j < deg; j++) {
            int s0 = __shfl(mycol, j);
            unsigned int u0 = G[(size_t)s0 * 64 + lane];
            ax += __uint_as_float(u0 << 16);
            ay += __uint_as_float(u0 & 0xffff0000u);
        }
        float2 b = *(const float2*)&bias[2 * lane];
        float2 o;
        o.x = fmaxf(fmaf(ax, r, b.x), 0.f);
        o.y = fmaxf(fmaf(ay, r, b.y), 0.f);
        *(float2*)&H[(size_t)v * 128 + 2 * lane] = o;
    } else {
        // row = 64 bf16 = 128 B; lane handles col lane
        const unsigned short* G = (const unsigned short*)Gv;
        float a = 0.f;
        int j = 0;
        for (; j + 3 < deg; j += 4) {
            int s0 = __shfl(mycol, j);
            int s1 = __shfl(mycol, j + 1);
            int s2 = __shfl(mycol, j + 2);
            int s3 = __shfl(mycol, j + 3);
            unsigned int u0 = G[(size_t)s0 * 64 + lane];
            unsigned int u1 = G[(size_t)s1 * 64 + lane];
            unsigned int u2 = G[(size_t)s2 * 64 + lane];
            unsigned int u3 = G[(size_t)s3 * 64 + lane];
            a += __uint_as_float(u0 << 16) + __uint_as_float(u1 << 16)
               + __uint_as_float(u2 << 16) + __uint_as_float(u3 << 16);
        }
        for (; j < deg; j++) {
            int s0 = __shfl(mycol, j);
            a += __uint_as_float(((unsigned int)G[(size_t)s0 * 64 + lane]) << 16);
        }
        float o = fmaxf(fmaf(a, r, bias[lane]), 0.f);
        H[(size_t)v * 64 + lane] = o;
    }
}

// ---------------- fused pooling + MLP + softmax (block per graph) ----------------
__global__ __launch_bounds__(256) void k_poolmlp(const float* __restrict__ h2,
                                                 const int* __restrict__ gid,
                                                 const float* __restrict__ fcW1,
                                                 const float* __restrict__ fcb1,
                                                 const float* __restrict__ fcW2,
                                                 const float* __restrict__ fcb2,
                                                 float* __restrict__ out) {
    __shared__ int se[2];
    __shared__ float part[4][64];
    __shared__ float p[64];
    __shared__ float z[10];
    __shared__ float l[10];
    __shared__ float red[2];
    const int g = blockIdx.x;
    const int tid = threadIdx.x;  // 256
    if (tid < 2) {
        int target = g + tid;  // lower_bound over sorted gid
        int lo = 0, hi = N_NODES;
        while (lo < hi) {
            int mid = (lo + hi) >> 1;
            if (gid[mid] < target) lo = mid + 1; else hi = mid;
        }
        se[tid] = lo;
    }
    __syncthreads();
    const int s = se[0], e = se[1];
    const int c = tid & 63;
    const int w = tid >> 6;
    float acc = 0.f;
    for (int v = s + w; v < e; v += 4) acc += h2[(size_t)v * 64 + c];
    part[w][c] = acc;
    __syncthreads();
    if (tid < 64) {
        float t = part[0][tid] + part[1][tid] + part[2][tid] + part[3][tid];
        p[tid] = t / (float)max(e - s, 1);
    }
    __syncthreads();
    if (tid < 10) {
        float a = fcb1[tid];
        for (int k = 0; k < 64; k++) a = fmaf(p[k], fcW1[k * 10 + tid], a);
        z[tid] = fmaxf(a, 0.f);
    }
    __syncthreads();
    if (tid < 10) {
        float a = fcb2[tid];
        for (int k = 0; k < 10; k++) a = fmaf(z[k], fcW2[k * 10 + tid], a);
        l[tid] = a;
    }
    __syncthreads();
    if (tid == 0) {
        float m = l[0];
        for (int i = 1; i < 10; i++) m = fmaxf(m, l[i]);
        float ssum = 0.f;
        for (int i = 0; i < 10; i++) ssum += expf(l[i] - m);
        red[0] = m;
        red[1] = ssum;
    }
    __syncthreads();
    if (tid < 10) out[g * 10 + tid] = expf(l[tid] - red[0]) / red[1];
}

// ---------------- host ----------------
extern "C" void kernel_launch(void* const* d_in, const int* in_sizes, int n_in,
                              void* d_out, int out_size, void* d_ws, size_t ws_size,
                              hipStream_t stream) {
    const float* feats = (const float*)d_in[0];
    const int* src = (const int*)d_in[1];
    const int* dst = (const int*)d_in[2];
    const int* gid = (const int*)d_in[3];
    const float* W1 = (const float*)d_in[4];
    const float* b1 = (const float*)d_in[5];
    const float* W2 = (const float*)d_in[6];
    const float* b2 = (const float*)d_in[7];
    const float* fcW1 = (const float*)d_in[8];
    const float* fcb1 = (const float*)d_in[9];
    const float* fcW2 = (const float*)d_in[10];
    const float* fcb2 = (const float*)d_in[11];
    float* out = (float*)d_out;

    char* w = (char*)d_ws;
    size_t off = 0;
    auto alloc = [&](size_t bytes) -> void* {
        void* p = w + off;
        off = (off + bytes + 255) & ~(size_t)255;
        return p;
    };
    int* cnt_out = (int*)alloc(N_NODES * 4);
    int* cnt_in  = (int*)alloc(N_NODES * 4);
    int* colsp   = (int*)alloc((size_t)N_NODES * MAXDEG * 4);         // 25.6 MB
    __hip_bfloat162* g1 = (__hip_bfloat162*)alloc((size_t)N_NODES * 128 * 2);  // 25.6 MB bf16
    float* h1 = (float*)alloc((size_t)N_NODES * 128 * 4);             // 51.2 MB
    __hip_bfloat162* g2 = (__hip_bfloat162*)alloc((size_t)N_NODES * 64 * 2);   // 12.8 MB bf16
    float* h2 = (float*)alloc((size_t)N_NODES * 64 * 4);              // 25.6 MB

    hipMemsetAsync(cnt_out, 0, N_NODES * 4, stream);
    hipMemsetAsync(cnt_in, 0, N_NODES * 4, stream);

    // adjacency + degrees, single pass
    k_build<<<N_EDGES / 256, 256, 0, stream>>>(src, dst, cnt_out, cnt_in, colsp);

    // layer 1
    k_gemm<128><<<dim3(N_NODES / 32, 2), 256, 0, stream>>>(feats, W1, cnt_out, g1);
    k_spmm<128><<<N_NODES / 4, 256, 0, stream>>>(g1, cnt_in, colsp, b1, h1);

    // layer 2
    k_gemm<64><<<dim3(N_NODES / 32, 1), 256, 0, stream>>>(h1, W2, cnt_out, g2);
    k_spmm<64><<<N_NODES / 4, 256, 0, stream>>>(g2, cnt_in, colsp, b2, h2);

    // pooling + MLP + softmax, fused
    k_poolmlp<<<N_GRAPHS, 256, 0, stream>>>(h2, gid, fcW1, fcb1, fcW2, fcb2, out);
}

// Round 4
// 454.659 us; speedup vs baseline: 1.6526x; 1.1944x over previous
//
#include <hip/hip_runtime.h>
#include <hip/hip_bf16.h>

#define N_NODES 100000
#define N_EDGES 1600000
#define N_GRAPHS 128
#define IN_F 128
#define H_F 128
#define OUT_F 64
#define HID 10
#define NCLS 10
#define MAXDEG 64   // in-degree ~ Poisson(16); P(deg>64) ~ 1e-20 per node
#define XPAD 136    // LDS row stride in bf16 (pad 128 -> 136: 16-way bank conflict -> free 2-way)

typedef __attribute__((ext_vector_type(8))) short bf16x8;
typedef __attribute__((ext_vector_type(4))) float f32x4;

// ---------------- single-pass padded-CSR build ----------------
__global__ void k_build(const int* __restrict__ src, const int* __restrict__ dst,
                        int* __restrict__ cnt_out, int* __restrict__ cnt_in,
                        int* __restrict__ colsp) {
    int e = blockIdx.x * blockDim.x + threadIdx.x;
    if (e < N_EDGES) {
        int s = src[e];
        int d = dst[e];
        atomicAdd(&cnt_out[s], 1);
        int idx = atomicAdd(&cnt_in[d], 1);
        if (idx < MAXDEG) colsp[d * MAXDEG + idx] = s;
    }
}

// ---------------- prep: bf16 transposed weights Wt[c][k] = W[k][c] ----------------
__global__ void k_prep(const float* __restrict__ W1, const float* __restrict__ W2,
                       unsigned short* __restrict__ Wt1, unsigned short* __restrict__ Wt2) {
    int t = blockIdx.x * blockDim.x + threadIdx.x;
    int stride = gridDim.x * blockDim.x;
    for (int i = t; i < 128 * 128; i += stride) {
        int c = i >> 7, k = i & 127;
        __hip_bfloat16 b = __float2bfloat16(W1[k * 128 + c]);
        Wt1[i] = *(unsigned short*)&b;
    }
    for (int i = t; i < 64 * 128; i += stride) {
        int c = i >> 7, k = i & 127;
        __hip_bfloat16 b = __float2bfloat16(W2[k * 64 + c]);
        Wt2[i] = *(unsigned short*)&b;
    }
}

// ---------------- MFMA GEMM: G[v, cbase..+63] = rsqrt(deg_out[v]) * (X[v,:] @ W[:, cbase..+63])
// K=128. X: f32 (XBF16=false) or bf16 (XBF16=true), row stride 128. Wt: bf16 [TOTF][128].
// Output bf16, row stride TOTF. Block 256 = 4 waves; tile 32 rows x 64 cols.
// Wave wv: rows (wv&1)*16..+15, cols (wv>>1)*32..+31 (two 16-col MFMA subtiles).
template <int TOTF, bool XBF16>
__global__ __launch_bounds__(256) void k_gemm_mfma(const void* __restrict__ Xv,
                                                   const unsigned short* __restrict__ Wt,
                                                   const int* __restrict__ cnt_out,
                                                   unsigned short* __restrict__ Gout) {
    __shared__ __align__(16) unsigned short Xs[32 * XPAD];
    __shared__ __align__(16) unsigned short Ws[64 * XPAD];
    const int tid = threadIdx.x;
    const int cbase = blockIdx.y * 64;
    const int row0 = blockIdx.x * 32;  // N_NODES % 32 == 0

    // stage X tile (32 rows x 128 k) as bf16 into Xs
    if constexpr (XBF16) {
        const uint2* X2 = (const uint2*)Xv;  // row = 32 uint2 (128 bf16)
#pragma unroll
        for (int j = 0; j < 4; j++) {
            int i = tid + 256 * j;           // 1024 uint2
            int r = i >> 5, kk = i & 31;
            uint2 u = X2[(size_t)(row0 + r) * 32 + kk];
            *(uint2*)&Xs[r * XPAD + kk * 4] = u;
        }
    } else {
        const float4* X4 = (const float4*)Xv;  // row = 32 float4
#pragma unroll
        for (int j = 0; j < 4; j++) {
            int i = tid + 256 * j;
            int r = i >> 5, k4 = i & 31;
            float4 x = X4[(size_t)(row0 + r) * 32 + k4];
            __hip_bfloat162 lo = __float22bfloat162_rn({x.x, x.y});
            __hip_bfloat162 hi = __float22bfloat162_rn({x.z, x.w});
            uint2 u;
            u.x = *(unsigned int*)&lo;
            u.y = *(unsigned int*)&hi;
            *(uint2*)&Xs[r * XPAD + k4 * 4] = u;
        }
    }
    // stage Wt rows [cbase, cbase+64): 64 x 128 bf16 into Ws
    {
        const uint2* W2 = (const uint2*)Wt;  // row = 32 uint2
#pragma unroll
        for (int j = 0; j < 8; j++) {
            int i = tid + 256 * j;           // 2048 uint2
            int c = i >> 5, kk = i & 31;
            uint2 u = W2[(size_t)(cbase + c) * 32 + kk];
            *(uint2*)&Ws[c * XPAD + kk * 4] = u;
        }
    }
    __syncthreads();

    const int lane = tid & 63;
    const int wv = tid >> 6;
    const int m = lane & 15;   // A row / B col / D col
    const int q = lane >> 4;   // quad
    const int roff = (wv & 1) * 16;
    const int coff = (wv >> 1) * 32;

    f32x4 acc0 = {0.f, 0.f, 0.f, 0.f}, acc1 = {0.f, 0.f, 0.f, 0.f};
#pragma unroll
    for (int ks = 0; ks < 4; ks++) {
        int kb = ks * 32 + q * 8;
        bf16x8 a  = *(const bf16x8*)&Xs[(roff + m) * XPAD + kb];
        bf16x8 b0 = *(const bf16x8*)&Ws[(coff + m) * XPAD + kb];
        bf16x8 b1 = *(const bf16x8*)&Ws[(coff + 16 + m) * XPAD + kb];
        acc0 = __builtin_amdgcn_mfma_f32_16x16x32_bf16(a, b0, acc0, 0, 0, 0);
        acc1 = __builtin_amdgcn_mfma_f32_16x16x32_bf16(a, b1, acc1, 0, 0, 0);
    }
    // D layout: col = lane&15, row = quad*4 + reg (verified m89/m91)
#pragma unroll
    for (int r = 0; r < 4; r++) {
        int row = row0 + roff + q * 4 + r;
        float s = rsqrtf((float)max(cnt_out[row], 1));
        int col0 = cbase + coff + m;
        __hip_bfloat16 o0 = __float2bfloat16(acc0[r] * s);
        __hip_bfloat16 o1 = __float2bfloat16(acc1[r] * s);
        Gout[(size_t)row * TOTF + col0]      = *(unsigned short*)&o0;
        Gout[(size_t)row * TOTF + col0 + 16] = *(unsigned short*)&o1;
    }
}

// ---------------- SpMM: H[v] = relu(rsqrt(deg_in[v]) * sum_{s in nbr(v)} G[s] + bias) ----------------
// wave per dst node; G packed bf16; H packed bf16.
template <int F>
__global__ __launch_bounds__(256) void k_spmm(const void* __restrict__ Gv,
                                              const int* __restrict__ cnt_in,
                                              const int* __restrict__ colsp,
                                              const float* __restrict__ bias,
                                              void* __restrict__ Hv) {
    const int lane = threadIdx.x & 63;
    const int wave = threadIdx.x >> 6;
    const int v = blockIdx.x * 4 + wave;   // N_NODES % 4 == 0
    if (v >= N_NODES) return;
    int cnt = cnt_in[v];
    int deg = min(cnt, MAXDEG);
    const int mycol = (lane < deg) ? colsp[v * MAXDEG + lane] : 0;
    const float r = rsqrtf((float)max(cnt, 1));
    if constexpr (F == 128) {
        const unsigned int* G = (const unsigned int*)Gv;  // row = 64 uint (128 bf16)
        float ax = 0.f, ay = 0.f;
        int j = 0;
        for (; j + 3 < deg; j += 4) {
            int s0 = __shfl(mycol, j);
            int s1 = __shfl(mycol, j + 1);
            int s2 = __shfl(mycol, j + 2);
            int s3 = __shfl(mycol, j + 3);
            unsigned int u0 = G[(size_t)s0 * 64 + lane];
            unsigned int u1 = G[(size_t)s1 * 64 + lane];
            unsigned int u2 = G[(size_t)s2 * 64 + lane];
            unsigned int u3 = G[(size_t)s3 * 64 + lane];
            ax += __uint_as_float(u0 << 16) + __uint_as_float(u1 << 16)
                + __uint_as_float(u2 << 16) + __uint_as_float(u3 << 16);
            ay += __uint_as_float(u0 & 0xffff0000u) + __uint_as_float(u1 & 0xffff0000u)
                + __uint_as_float(u2 & 0xffff0000u) + __uint_as_float(u3 & 0xffff0000u);
        }
        for (; j < deg; j++) {
            int s0 = __shfl(mycol, j);
            unsigned int u0 = G[(size_t)s0 * 64 + lane];
            ax += __uint_as_float(u0 << 16);
            ay += __uint_as_float(u0 & 0xffff0000u);
        }
        float2 b = *(const float2*)&bias[2 * lane];
        float2 o;
        o.x = fmaxf(fmaf(ax, r, b.x), 0.f);
        o.y = fmaxf(fmaf(ay, r, b.y), 0.f);
        __hip_bfloat162 ob = __float22bfloat162_rn(o);
        ((unsigned int*)Hv)[(size_t)v * 64 + lane] = *(unsigned int*)&ob;
    } else {
        const unsigned short* G = (const unsigned short*)Gv;  // row = 64 bf16
        float a = 0.f;
        int j = 0;
        for (; j + 3 < deg; j += 4) {
            int s0 = __shfl(mycol, j);
            int s1 = __shfl(mycol, j + 1);
            int s2 = __shfl(mycol, j + 2);
            int s3 = __shfl(mycol, j + 3);
            unsigned int u0 = G[(size_t)s0 * 64 + lane];
            unsigned int u1 = G[(size_t)s1 * 64 + lane];
            unsigned int u2 = G[(size_t)s2 * 64 + lane];
            unsigned int u3 = G[(size_t)s3 * 64 + lane];
            a += __uint_as_float(u0 << 16) + __uint_as_float(u1 << 16)
               + __uint_as_float(u2 << 16) + __uint_as_float(u3 << 16);
        }
        for (; j < deg; j++) {
            int s0 = __shfl(mycol, j);
            a += __uint_as_float(((unsigned int)G[(size_t)s0 * 64 + lane]) << 16);
        }
        float o = fmaxf(fmaf(a, r, bias[lane]), 0.f);
        __hip_bfloat16 ob = __float2bfloat16(o);
        ((unsigned short*)Hv)[(size_t)v * 64 + lane] = *(unsigned short*)&ob;
    }
}

// ---------------- fused pooling + MLP + softmax (block per graph; h2 bf16) ----------------
__global__ __launch_bounds__(256) void k_poolmlp(const unsigned short* __restrict__ h2,
                                                 const int* __restrict__ gid,
                                                 const float* __restrict__ fcW1,
                                                 const float* __restrict__ fcb1,
                                                 const float* __restrict__ fcW2,
                                                 const float* __restrict__ fcb2,
                                                 float* __restrict__ out) {
    __shared__ int se[2];
    __shared__ float part[4][64];
    __shared__ float p[64];
    __shared__ float z[10];
    __shared__ float l[10];
    __shared__ float red[2];
    const int g = blockIdx.x;
    const int tid = threadIdx.x;  // 256
    if (tid < 2) {
        int target = g + tid;  // lower_bound over sorted gid
        int lo = 0, hi = N_NODES;
        while (lo < hi) {
            int mid = (lo + hi) >> 1;
            if (gid[mid] < target) lo = mid + 1; else hi = mid;
        }
        se[tid] = lo;
    }
    __syncthreads();
    const int s = se[0], e = se[1];
    const int c = tid & 63;
    const int w = tid >> 6;
    float acc = 0.f;
    for (int v = s + w; v < e; v += 4)
        acc += __uint_as_float(((unsigned int)h2[(size_t)v * 64 + c]) << 16);
    part[w][c] = acc;
    __syncthreads();
    if (tid < 64) {
        float t = part[0][tid] + part[1][tid] + part[2][tid] + part[3][tid];
        p[tid] = t / (float)max(e - s, 1);
    }
    __syncthreads();
    if (tid < 10) {
        float a = fcb1[tid];
        for (int k = 0; k < 64; k++) a = fmaf(p[k], fcW1[k * 10 + tid], a);
        z[tid] = fmaxf(a, 0.f);
    }
    __syncthreads();
    if (tid < 10) {
        float a = fcb2[tid];
        for (int k = 0; k < 10; k++) a = fmaf(z[k], fcW2[k * 10 + tid], a);
        l[tid] = a;
    }
    __syncthreads();
    if (tid == 0) {
        float m = l[0];
        for (int i = 1; i < 10; i++) m = fmaxf(m, l[i]);
        float ssum = 0.f;
        for (int i = 0; i < 10; i++) ssum += expf(l[i] - m);
        red[0] = m;
        red[1] = ssum;
    }
    __syncthreads();
    if (tid < 10) out[g * 10 + tid] = expf(l[tid] - red[0]) / red[1];
}

// ---------------- host ----------------
extern "C" void kernel_launch(void* const* d_in, const int* in_sizes, int n_in,
                              void* d_out, int out_size, void* d_ws, size_t ws_size,
                              hipStream_t stream) {
    const float* feats = (const float*)d_in[0];
    const int* src = (const int*)d_in[1];
    const int* dst = (const int*)d_in[2];
    const int* gid = (const int*)d_in[3];
    const float* W1 = (const float*)d_in[4];
    const float* b1 = (const float*)d_in[5];
    const float* W2 = (const float*)d_in[6];
    const float* b2 = (const float*)d_in[7];
    const float* fcW1 = (const float*)d_in[8];
    const float* fcb1 = (const float*)d_in[9];
    const float* fcW2 = (const float*)d_in[10];
    const float* fcb2 = (const float*)d_in[11];
    float* out = (float*)d_out;

    char* w = (char*)d_ws;
    size_t off = 0;
    auto alloc = [&](size_t bytes) -> void* {
        void* p = w + off;
        off = (off + bytes + 255) & ~(size_t)255;
        return p;
    };
    int* cnt_out = (int*)alloc(N_NODES * 4 * 2);   // cnt_out + cnt_in adjacent (single memset)
    int* cnt_in  = cnt_out + N_NODES;
    int* colsp   = (int*)alloc((size_t)N_NODES * MAXDEG * 4);              // 25.6 MB
    unsigned short* Wt1 = (unsigned short*)alloc(128 * 128 * 2);           // bf16 W1^T
    unsigned short* Wt2 = (unsigned short*)alloc(64 * 128 * 2);            // bf16 W2^T
    unsigned short* g1 = (unsigned short*)alloc((size_t)N_NODES * 128 * 2);  // bf16
    unsigned short* h1 = (unsigned short*)alloc((size_t)N_NODES * 128 * 2);  // bf16
    unsigned short* g2 = (unsigned short*)alloc((size_t)N_NODES * 64 * 2);   // bf16
    unsigned short* h2 = (unsigned short*)alloc((size_t)N_NODES * 64 * 2);   // bf16

    hipMemsetAsync(cnt_out, 0, N_NODES * 4 * 2, stream);

    // adjacency + degrees (single pass) and bf16 transposed weights
    k_build<<<N_EDGES / 256, 256, 0, stream>>>(src, dst, cnt_out, cnt_in, colsp);
    k_prep<<<32, 256, 0, stream>>>(W1, W2, Wt1, Wt2);

    // layer 1
    k_gemm_mfma<128, false><<<dim3(N_NODES / 32, 2), 256, 0, stream>>>(feats, Wt1, cnt_out, g1);
    k_spmm<128><<<N_NODES / 4, 256, 0, stream>>>(g1, cnt_in, colsp, b1, h1);

    // layer 2
    k_gemm_mfma<64, true><<<dim3(N_NODES / 32, 1), 256, 0, stream>>>(h1, Wt2, cnt_out, g2);
    k_spmm<64><<<N_NODES / 4, 256, 0, stream>>>(g2, cnt_in, colsp, b2, h2);

    // pooling + MLP + softmax, fused
    k_poolmlp<<<N_GRAPHS, 256, 0, stream>>>(h2, gid, fcW1, fcb1, fcW2, fcb2, out);
}